// Round 7
// baseline (160.190 us; speedup 1.0000x reference)
//
#include <hip/hip_runtime.h>
#include <hip/hip_bf16.h>

#define HH 200
#define WW 176
#define CIN 256
#define CO 28
#define XH 202
#define XW 178
#define BN_EPS 1e-3f

typedef __attribute__((ext_vector_type(8))) short short8;
typedef __attribute__((ext_vector_type(4))) float f32x4;

static __device__ __forceinline__ ushort f2bf(float f) {
    __hip_bfloat16 h = __float2bfloat16(f);
    return __builtin_bit_cast(ushort, h);
}

// ---------------------------------------------------------------------------
// prep: w1b chunk-major [h][t][n][lane][j] (bf16, BN-folded), plus shift[28].
//   co = n*16 + (lane&15), ci = h*32 + (lane>>4)*8 + j
// ---------------------------------------------------------------------------
__global__ void prep_k(const float* __restrict__ w1, const float* __restrict__ gamma,
                       const float* __restrict__ beta, const float* __restrict__ mean,
                       const float* __restrict__ var, ushort* __restrict__ w1b,
                       float* __restrict__ shift)
{
    int idx = blockIdx.x * 256 + threadIdx.x;
    if (idx < CO) {
        float sc = gamma[idx] * rsqrtf(var[idx] + BN_EPS);
        shift[idx] = beta[idx] - mean[idx] * sc;
    }
    if (idx < 8 * 9 * 2 * 64 * 8) {
        int j   = idx & 7;
        int l   = (idx >> 3) & 63;
        int n   = (idx >> 9) & 1;
        int rem = idx >> 10;          // h*9 + t
        int t   = rem % 9;
        int h   = rem / 9;
        int co = n * 16 + (l & 15);
        int ci = h * 32 + (l >> 4) * 8 + j;
        float v = 0.f;
        if (co < CO) {
            float sc = gamma[co] * rsqrtf(var[co] + BN_EPS);
            v = w1[(co * CIN + ci) * 9 + t] * sc;
        }
        w1b[idx] = f2bf(v);
    }
}

// ---------------------------------------------------------------------------
// pad: zero the 1-px border of xtp (padded NHWC bf16). Border rows fill the
// whole row; interior rows fill px 0 and XW-1.
// ---------------------------------------------------------------------------
__global__ __launch_bounds__(256) void pad_k(ushort* __restrict__ xtp)
{
    const int row = blockIdx.x;            // b*XH + y, 0..4*XH-1
    const int y   = row % XH;
    uint4* base = (uint4*)(xtp + (size_t)row * XW * 256);
    const uint4 z = {0u, 0u, 0u, 0u};
    if (y == 0 || y == XH - 1) {
        for (int i = threadIdx.x; i < XW * 32; i += 256) base[i] = z;
    } else if (threadIdx.x < 64) {
        int px = threadIdx.x >> 5;         // 0 or 1
        int i  = threadIdx.x & 31;
        base[(px ? (XW - 1) : 0) * 32 + i] = z;
    }
}

// ---------------------------------------------------------------------------
// transpose+convert: x [b][ci][y][xx] f32  ->  xtp [b][y+1][xx+1][ci] bf16.
// Block = one (b, y, 16-px chunk). thread: px = t&15, ci-group = t>>4 (16 ci).
// Reads coalesced along W (16x4B per lane-group); writes: a wave's 64 lanes
// cover 16 pixels x 128B -> all-full-line stores.
// ---------------------------------------------------------------------------
__global__ __launch_bounds__(256) void xt_k(const float* __restrict__ x,
                                            ushort* __restrict__ xtp)
{
    const int bid = blockIdx.x;            // 4*200*11
    const int xc  = bid % 11;
    const int rem = bid / 11;
    const int y   = rem % HH;
    const int b   = rem / HH;
    const int px  = threadIdx.x & 15;
    const int cig = threadIdx.x >> 4;      // 0..15 (16 ci each)
    const int gx  = xc * 16 + px;

    const float* xp = x + ((size_t)b * CIN + cig * 16) * (HH * WW) + y * WW + gx;
    float v[16];
#pragma unroll
    for (int j = 0; j < 16; ++j) v[j] = xp[(size_t)j * (HH * WW)];

    ushort u[16];
#pragma unroll
    for (int j = 0; j < 16; ++j) u[j] = f2bf(v[j]);

    uint4 a, c;
    a.x = (uint)u[0]  | ((uint)u[1]  << 16);
    a.y = (uint)u[2]  | ((uint)u[3]  << 16);
    a.z = (uint)u[4]  | ((uint)u[5]  << 16);
    a.w = (uint)u[6]  | ((uint)u[7]  << 16);
    c.x = (uint)u[8]  | ((uint)u[9]  << 16);
    c.y = (uint)u[10] | ((uint)u[11] << 16);
    c.z = (uint)u[12] | ((uint)u[13] << 16);
    c.w = (uint)u[14] | ((uint)u[15] << 16);

    ushort* dst = xtp + (((size_t)(b * XH + y + 1)) * XW + gx + 1) * 256 + cig * 16;
    ((uint4*)dst)[0] = a;
    ((uint4*)dst)[1] = c;
}

// ---------------------------------------------------------------------------
// Implicit-GEMM conv3x3 + BN + ReLU via bf16 MFMA — LDS-free, barrier-free.
// Tile 16x8 px, 4 waves; wave w owns rows {2w, 2w+1}. A-frags loaded DIRECTLY
// from padded NHWC bf16 xtp (one b128/lane per frag, no masking thanks to the
// zero border). Weights direct b128 (L1-hot). Waves fully independent.
// ---------------------------------------------------------------------------
__global__ __launch_bounds__(256, 4) void conv_mfma_k(
    const ushort* __restrict__ xtp, const ushort* __restrict__ w1b,
    const float* __restrict__ shift, float* __restrict__ y1)
{
    const int tid  = threadIdx.x;
    const int lane = tid & 63;
    const int w    = tid >> 6;

    // XCD-aware bijective block swizzle (1100 blocks, 8 XCDs)
    const int NB = 11 * 25 * 4;
    const int q = NB / 8, r = NB % 8;     // 137, 4
    const int bid  = blockIdx.x;
    const int xcd  = bid & 7;
    const int rank = bid >> 3;
    const int tile = (xcd < r ? xcd * (q + 1) : r * (q + 1) + (xcd - r) * q) + rank;

    const int tx  = tile % 11;
    const int rem = tile / 11;
    const int ty  = rem % 25;
    const int b   = rem / 25;
    const int x0  = tx * 16, y0 = ty * 8;

    const int c_  = lane & 15;
    const int oct = lane >> 4;

    // frag(rl, dx) pixel = image (y0+2w-1+rl, x0+c_-1+dx) -> padded (+1, +1)
    const ushort* abase = xtp
        + (((size_t)(b * XH + y0 + 2 * w) * XW) + x0 + c_) * 256 + oct * 8;

    f32x4 acc[2][2];
#pragma unroll
    for (int m = 0; m < 2; ++m)
#pragma unroll
        for (int n = 0; n < 2; ++n)
            acc[m][n] = (f32x4){0.f, 0.f, 0.f, 0.f};

#pragma unroll 1
    for (int h = 0; h < 8; ++h) {
        const ushort* ab = abase + h * 32;
        short8 av[4][3];
#pragma unroll
        for (int rl = 0; rl < 4; ++rl)
#pragma unroll
            for (int dx = 0; dx < 3; ++dx)
                av[rl][dx] = *(const short8*)(ab + ((size_t)rl * XW + dx) * 256);

        const ushort* wsrc = w1b + (size_t)h * 9216 + lane * 8;
#pragma unroll
        for (int t = 0; t < 9; ++t) {
            const int dy = t / 3, dx = t % 3;
            short8 b0 = *(const short8*)(wsrc + (size_t)(t * 2 + 0) * 512);
            short8 b1 = *(const short8*)(wsrc + (size_t)(t * 2 + 1) * 512);
#pragma unroll
            for (int m = 0; m < 2; ++m) {
                short8 af = av[m + dy][dx];
                acc[m][0] = __builtin_amdgcn_mfma_f32_16x16x32_bf16(af, b0, acc[m][0], 0, 0, 0);
                acc[m][1] = __builtin_amdgcn_mfma_f32_16x16x32_bf16(af, b1, acc[m][1], 0, 0, 0);
            }
        }
    }

    // epilogue: + shift, ReLU, store channel-last y1
    const int co0 = c_;
    const int co1 = 16 + c_;
    const float s0 = shift[co0];
    const float s1 = (co1 < CO) ? shift[co1] : 0.f;
#pragma unroll
    for (int m = 0; m < 2; ++m) {
        int gy = y0 + 2 * w + m;
#pragma unroll
        for (int reg = 0; reg < 4; ++reg) {
            int gx = x0 + oct * 4 + reg;
            float* yp = y1 + ((size_t)(b * HH + gy) * WW + gx) * CO;
            float v0 = acc[m][0][reg] + s0;
            yp[co0] = v0 > 0.f ? v0 : 0.f;
            if (co1 < CO) {
                float v1 = acc[m][1][reg] + s1;
                yp[co1] = v1 > 0.f ? v1 : 0.f;
            }
        }
    }
}

// ---------------------------------------------------------------------------
// Sampler: thread = (box, k).  Bilinear sample of conv1x1 output = conv1x1 of
// bilinear samples (linear, bias-free).  Mean over k via LDS reduce.
// ---------------------------------------------------------------------------
__global__ __launch_bounds__(224) void sample_k(
    const float* __restrict__ y1, const float* __restrict__ ga,
    const float* __restrict__ w2, float* __restrict__ out)
{
    __shared__ float red[224];
    const int lb  = threadIdx.x / CO;   // local box 0..7
    const int k   = threadIdx.x % CO;   // window index / channel
    const int box = blockIdx.x * 8 + lb;
    const int b   = box >> 11;          // / 2048

    const float* ap = ga + (size_t)box * 7;
    float xg = ap[0], yg = ap[1], wg = ap[3], lg = ap[4], rg = ap[6];
    float c = cosf(rg), s = sinf(rg);

    const int i = k / 7, j = k % 7;
    float xx = ((float)i * (1.f / 3.f) - 0.5f) * wg;
    float yy = ((float)j * (1.f / 6.f) - 0.5f) * lg;
    float xs = (xx * c + yy * s + xg) * 2.5f;
    float ys = (yy * c - xx * s + yg + 40.f) * 2.5f;

    float x0 = floorf(xs), y0 = floorf(ys);
    float wx = xs - x0,    wy = ys - y0;

    float w2r[CO];
    const float* w2p = w2 + k * CO;
#pragma unroll
    for (int q = 0; q < 7; ++q) {
        float4 t = ((const float4*)w2p)[q];
        w2r[4*q] = t.x; w2r[4*q+1] = t.y; w2r[4*q+2] = t.z; w2r[4*q+3] = t.w;
    }

    float val = 0.f;
    const float* yb = y1 + (size_t)b * HH * WW * CO;
#pragma unroll
    for (int cor = 0; cor < 4; ++cor) {
        float yf = y0 + (float)(cor >> 1);
        float xf = x0 + (float)(cor & 1);
        float cw = ((cor & 1) ? wx : 1.f - wx) * ((cor >> 1) ? wy : 1.f - wy);
        if (yf >= 0.f && yf <= (float)(HH - 1) && xf >= 0.f && xf <= (float)(WW - 1)) {
            int yi = (int)yf, xi = (int)xf;
            const float* p = yb + ((size_t)yi * WW + xi) * CO;
            float d = 0.f;
#pragma unroll
            for (int q = 0; q < 7; ++q) {
                float4 t = ((const float4*)p)[q];
                d = fmaf(w2r[4*q],   t.x, d);
                d = fmaf(w2r[4*q+1], t.y, d);
                d = fmaf(w2r[4*q+2], t.z, d);
                d = fmaf(w2r[4*q+3], t.w, d);
            }
            val = fmaf(cw, d, val);
        }
    }

    red[threadIdx.x] = val;
    __syncthreads();
    if (k == 0) {
        float sum = 0.f;
#pragma unroll
        for (int q = 0; q < CO; ++q) sum += red[lb * CO + q];
        out[box] = sum * (1.f / 28.f);
    }
}

// ---------------------------------------------------------------------------
extern "C" void kernel_launch(void* const* d_in, const int* in_sizes, int n_in,
                              void* d_out, int out_size, void* d_ws, size_t ws_size,
                              hipStream_t stream) {
    const float* x     = (const float*)d_in[0];
    const float* ga    = (const float*)d_in[1];
    const float* w1    = (const float*)d_in[2];
    const float* gamma = (const float*)d_in[3];
    const float* beta  = (const float*)d_in[4];
    const float* mean  = (const float*)d_in[5];
    const float* var   = (const float*)d_in[6];
    const float* w2    = (const float*)d_in[7];
    float* out = (float*)d_out;

    // workspace layout
    ushort* w1b   = (ushort*)d_ws;                          // 147456 B
    float*  shift = (float*)((char*)d_ws + 147456);         // 112 B
    ushort* xtp   = (ushort*)((char*)d_ws + 147968);        // 4*202*178*256*2 = 73,637,888 B
    float*  y1    = (float*)((char*)d_ws + 147968 + 73637888); // 4*200*176*28*4 B

    prep_k<<<(8 * 9 * 2 * 64 * 8 + 255) / 256, 256, 0, stream>>>(
        w1, gamma, beta, mean, var, w1b, shift);

    pad_k<<<4 * XH, 256, 0, stream>>>(xtp);
    xt_k<<<4 * HH * 11, 256, 0, stream>>>(x, xtp);

    conv_mfma_k<<<11 * 25 * 4, 256, 0, stream>>>(xtp, w1b, shift, y1);

    sample_k<<<(4 * 2048) / 8, 224, 0, stream>>>(y1, ga, w2, out);
}

// Round 8
// 84.191 us; speedup vs baseline: 1.9027x; 1.9027x over previous
//
#include <hip/hip_runtime.h>
#include <hip/hip_bf16.h>

#define HH 200
#define WW 176
#define CIN 256
#define CO 28
#define BN_EPS 1e-3f

typedef __attribute__((ext_vector_type(8))) short short8;
typedef __attribute__((ext_vector_type(4))) float f32x4;

static __device__ __forceinline__ ushort f2bf(float f) {
    __hip_bfloat16 h = __float2bfloat16(f);
    return __builtin_bit_cast(ushort, h);
}

// ---------------------------------------------------------------------------
// prep: w1b chunk-major [h][t][n][lane][j] (bf16, BN-folded), plus shift[28].
//   co = n*16 + (lane&15), ci = h*32 + (lane>>4)*8 + j
// ---------------------------------------------------------------------------
__global__ void prep_k(const float* __restrict__ w1, const float* __restrict__ gamma,
                       const float* __restrict__ beta, const float* __restrict__ mean,
                       const float* __restrict__ var, ushort* __restrict__ w1b,
                       float* __restrict__ shift)
{
    int idx = blockIdx.x * 256 + threadIdx.x;
    if (idx < CO) {
        float sc = gamma[idx] * rsqrtf(var[idx] + BN_EPS);
        shift[idx] = beta[idx] - mean[idx] * sc;
    }
    if (idx < 8 * 9 * 2 * 64 * 8) {
        int j   = idx & 7;
        int l   = (idx >> 3) & 63;
        int n   = (idx >> 9) & 1;
        int rem = idx >> 10;          // h*9 + t
        int t   = rem % 9;
        int h   = rem / 9;
        int co = n * 16 + (l & 15);
        int ci = h * 32 + (l >> 4) * 8 + j;
        float v = 0.f;
        if (co < CO) {
            float sc = gamma[co] * rsqrtf(var[co] + BN_EPS);
            v = w1[(co * CIN + ci) * 9 + t] * sc;
        }
        w1b[idx] = f2bf(v);
    }
}

// ---------------------------------------------------------------------------
// Implicit-GEMM conv3x3 + BN + ReLU via bf16 MFMA.
// Tile 16x8 px, 4 waves; wave w owns rows {2w,2w+1}, stages ci-octet w.
// x halo 18x10 px x 32ci bf16, double-buffered LDS (16B-unit swizzle).
// 2-DEEP register pipeline: x(h+2) issued at chunk h, waited at chunk h+1's
// ds_write -> a full chunk of compute covers global latency. One barrier per
// chunk. Weights: direct global (L1-hot) with 2-tap register lookahead.
// ---------------------------------------------------------------------------
__global__ __launch_bounds__(256, 3) void conv_mfma_k(
    const float* __restrict__ x, const ushort* __restrict__ w1b,
    const float* __restrict__ shift, float* __restrict__ y1)
{
    __shared__ uint4 sbuf[2][180 * 4];    // 2 x 11520 B

    const int tid  = threadIdx.x;
    const int lane = tid & 63;
    const int w    = tid >> 6;            // wave id == ci octet

    // XCD-aware bijective block swizzle (1100 blocks, 8 XCDs)
    const int NB = 11 * 25 * 4;
    const int q = NB / 8, r = NB % 8;     // 137, 4
    const int bid  = blockIdx.x;
    const int xcd  = bid & 7;
    const int rank = bid >> 3;
    const int tile = (xcd < r ? xcd * (q + 1) : r * (q + 1) + (xcd - r) * q) + rank;

    const int tx  = tile % 11;
    const int rem = tile / 11;
    const int ty  = rem % 25;
    const int b   = rem / 25;
    const int x0  = tx * 16, y0 = ty * 8;

    const float* xb = x + (size_t)b * CIN * HH * WW;

    // chunk-invariant per-lane staging geometry (halo 18 wide x 10 tall)
    int  soff[3]; bool sval[3]; bool sp[3];
#pragma unroll
    for (int it = 0; it < 3; ++it) {
        int p = it * 64 + lane;
        sp[it] = p < 180;
        int rr = p / 18, cc = p - rr * 18;
        int gy = y0 + rr - 1, gx = x0 + cc - 1;
        bool v = (gy >= 0) & (gy < HH) & (gx >= 0) & (gx < WW) & sp[it];
        sval[it] = v;
        soff[it] = v ? gy * WW + gx : 0;
    }

    float pre0[3][8], pre1[3][8];

    f32x4 acc[2][2];
#pragma unroll
    for (int m = 0; m < 2; ++m)
#pragma unroll
        for (int n = 0; n < 2; ++n)
            acc[m][n] = (f32x4){0.f, 0.f, 0.f, 0.f};

#define ISSUE_X(h, PRE)                                                     \
    {                                                                       \
        const float* pl = xb + (size_t)((h) * 32 + w * 8) * (HH * WW);      \
        _Pragma("unroll")                                                   \
        for (int it = 0; it < 3; ++it) {                                    \
            if (sp[it]) {                                                   \
                _Pragma("unroll")                                           \
                for (int j = 0; j < 8; ++j)                                 \
                    PRE[it][j] = pl[(size_t)j * (HH * WW) + soff[it]];      \
            }                                                               \
        }                                                                   \
    }

#define WR_X(PRE, BI)                                                       \
    {                                                                       \
        _Pragma("unroll")                                                   \
        for (int it = 0; it < 3; ++it) {                                    \
            if (sp[it]) {                                                   \
                int p = it * 64 + lane;                                     \
                ushort u[8];                                                \
                _Pragma("unroll")                                           \
                for (int j = 0; j < 8; ++j)                                 \
                    u[j] = sval[it] ? f2bf(PRE[it][j]) : (ushort)0;         \
                uint4 val;                                                  \
                val.x = (uint)u[0] | ((uint)u[1] << 16);                    \
                val.y = (uint)u[2] | ((uint)u[3] << 16);                    \
                val.z = (uint)u[4] | ((uint)u[5] << 16);                    \
                val.w = (uint)u[6] | ((uint)u[7] << 16);                    \
                sbuf[BI][p * 4 + ((w + p) & 3)] = val;                      \
            }                                                               \
        }                                                                   \
    }

#define COMPUTE(h)                                                          \
    {                                                                       \
        const uint4* sb = sbuf[(h) & 1];                                    \
        short8 av[4][3];                                                    \
        _Pragma("unroll")                                                   \
        for (int rl = 0; rl < 4; ++rl) {                                    \
            _Pragma("unroll")                                               \
            for (int dx = 0; dx < 3; ++dx) {                                \
                int p = (2 * w + rl) * 18 + (lane & 15) + dx;               \
                av[rl][dx] = __builtin_bit_cast(short8,                     \
                    sb[p * 4 + (((lane >> 4) + p) & 3)]);                   \
            }                                                               \
        }                                                                   \
        const ushort* wsrc = w1b + (size_t)(h) * 9216 + lane * 8;           \
        short8 wq[3][2];                                                    \
        _Pragma("unroll")                                                   \
        for (int n = 0; n < 2; ++n) {                                       \
            wq[0][n] = *(const short8*)(wsrc + (size_t)(0 * 2 + n) * 512);  \
            wq[1][n] = *(const short8*)(wsrc + (size_t)(1 * 2 + n) * 512);  \
        }                                                                   \
        _Pragma("unroll")                                                   \
        for (int t = 0; t < 9; ++t) {                                       \
            if (t + 2 < 9) {                                                \
                _Pragma("unroll")                                           \
                for (int n = 0; n < 2; ++n)                                 \
                    wq[(t + 2) % 3][n] =                                    \
                        *(const short8*)(wsrc + (size_t)((t + 2) * 2 + n) * 512); \
            }                                                               \
            const int dy = t / 3, dx = t % 3;                               \
            _Pragma("unroll")                                               \
            for (int m = 0; m < 2; ++m) {                                   \
                short8 af = av[m + dy][dx];                                 \
                acc[m][0] = __builtin_amdgcn_mfma_f32_16x16x32_bf16(        \
                    af, wq[t % 3][0], acc[m][0], 0, 0, 0);                  \
                acc[m][1] = __builtin_amdgcn_mfma_f32_16x16x32_bf16(        \
                    af, wq[t % 3][1], acc[m][1], 0, 0, 0);                  \
            }                                                               \
        }                                                                   \
    }

// one chunk: issue x(h+2) -> fence -> compute(h) -> wr x(h+1) -> barrier
#define STEP(h, PREI, PREW)                                                 \
    {                                                                       \
        if ((h) + 2 < 8) ISSUE_X((h) + 2, PREI);                            \
        __builtin_amdgcn_sched_barrier(0);                                  \
        COMPUTE(h);                                                         \
        if ((h) < 7) {                                                      \
            WR_X(PREW, ((h) + 1) & 1);                                      \
            __syncthreads();                                                \
        }                                                                   \
    }

    // prologue: x(0), x(1) in flight; stage x(0); barrier
    ISSUE_X(0, pre0);
    ISSUE_X(1, pre1);
    WR_X(pre0, 0);
    __syncthreads();

    STEP(0, pre0, pre1);   // issue x2->pre0, compute 0, write x1->sbuf1
    STEP(1, pre1, pre0);   // issue x3->pre1, compute 1, write x2->sbuf0
    STEP(2, pre0, pre1);
    STEP(3, pre1, pre0);
    STEP(4, pre0, pre1);
    STEP(5, pre1, pre0);
    STEP(6, pre0, pre1);   // no issue, compute 6, write x7->sbuf1
    STEP(7, pre1, pre0);   // compute 7 only

    // epilogue: + shift, ReLU, store channel-last y1
    const int co0 = lane & 15;
    const int co1 = 16 + co0;
    const float s0 = shift[co0];
    const float s1 = (co1 < CO) ? shift[co1] : 0.f;
#pragma unroll
    for (int m = 0; m < 2; ++m) {
        int gy = y0 + 2 * w + m;
#pragma unroll
        for (int reg = 0; reg < 4; ++reg) {
            int gx = x0 + (lane >> 4) * 4 + reg;
            float* yp = y1 + ((size_t)(b * HH + gy) * WW + gx) * CO;
            float v0 = acc[m][0][reg] + s0;
            yp[co0] = v0 > 0.f ? v0 : 0.f;
            if (co1 < CO) {
                float v1 = acc[m][1][reg] + s1;
                yp[co1] = v1 > 0.f ? v1 : 0.f;
            }
        }
    }
}

// ---------------------------------------------------------------------------
// Sampler: thread = (box, k).  Bilinear sample of conv1x1 output = conv1x1 of
// bilinear samples (linear, bias-free).  Mean over k via LDS reduce.
// ---------------------------------------------------------------------------
__global__ __launch_bounds__(224) void sample_k(
    const float* __restrict__ y1, const float* __restrict__ ga,
    const float* __restrict__ w2, float* __restrict__ out)
{
    __shared__ float red[224];
    const int lb  = threadIdx.x / CO;   // local box 0..7
    const int k   = threadIdx.x % CO;   // window index / channel
    const int box = blockIdx.x * 8 + lb;
    const int b   = box >> 11;          // / 2048

    const float* ap = ga + (size_t)box * 7;
    float xg = ap[0], yg = ap[1], wg = ap[3], lg = ap[4], rg = ap[6];
    float c = cosf(rg), s = sinf(rg);

    const int i = k / 7, j = k % 7;
    float xx = ((float)i * (1.f / 3.f) - 0.5f) * wg;
    float yy = ((float)j * (1.f / 6.f) - 0.5f) * lg;
    float xs = (xx * c + yy * s + xg) * 2.5f;
    float ys = (yy * c - xx * s + yg + 40.f) * 2.5f;

    float x0 = floorf(xs), y0 = floorf(ys);
    float wx = xs - x0,    wy = ys - y0;

    float w2r[CO];
    const float* w2p = w2 + k * CO;
#pragma unroll
    for (int q = 0; q < 7; ++q) {
        float4 t = ((const float4*)w2p)[q];
        w2r[4*q] = t.x; w2r[4*q+1] = t.y; w2r[4*q+2] = t.z; w2r[4*q+3] = t.w;
    }

    float val = 0.f;
    const float* yb = y1 + (size_t)b * HH * WW * CO;
#pragma unroll
    for (int cor = 0; cor < 4; ++cor) {
        float yf = y0 + (float)(cor >> 1);
        float xf = x0 + (float)(cor & 1);
        float cw = ((cor & 1) ? wx : 1.f - wx) * ((cor >> 1) ? wy : 1.f - wy);
        if (yf >= 0.f && yf <= (float)(HH - 1) && xf >= 0.f && xf <= (float)(WW - 1)) {
            int yi = (int)yf, xi = (int)xf;
            const float* p = yb + ((size_t)yi * WW + xi) * CO;
            float d = 0.f;
#pragma unroll
            for (int q = 0; q < 7; ++q) {
                float4 t = ((const float4*)p)[q];
                d = fmaf(w2r[4*q],   t.x, d);
                d = fmaf(w2r[4*q+1], t.y, d);
                d = fmaf(w2r[4*q+2], t.z, d);
                d = fmaf(w2r[4*q+3], t.w, d);
            }
            val = fmaf(cw, d, val);
        }
    }

    red[threadIdx.x] = val;
    __syncthreads();
    if (k == 0) {
        float sum = 0.f;
#pragma unroll
        for (int q = 0; q < CO; ++q) sum += red[lb * CO + q];
        out[box] = sum * (1.f / 28.f);
    }
}

// ---------------------------------------------------------------------------
extern "C" void kernel_launch(void* const* d_in, const int* in_sizes, int n_in,
                              void* d_out, int out_size, void* d_ws, size_t ws_size,
                              hipStream_t stream) {
    const float* x     = (const float*)d_in[0];
    const float* ga    = (const float*)d_in[1];
    const float* w1    = (const float*)d_in[2];
    const float* gamma = (const float*)d_in[3];
    const float* beta  = (const float*)d_in[4];
    const float* mean  = (const float*)d_in[5];
    const float* var   = (const float*)d_in[6];
    const float* w2    = (const float*)d_in[7];
    float* out = (float*)d_out;

    ushort* w1b   = (ushort*)d_ws;                         // 147456 B
    float*  shift = (float*)((char*)d_ws + 147456);        // 112 B
    float*  y1    = (float*)((char*)d_ws + 147968);        // 4*200*176*28 f32

    prep_k<<<(8 * 9 * 2 * 64 * 8 + 255) / 256, 256, 0, stream>>>(
        w1, gamma, beta, mean, var, w1b, shift);

    conv_mfma_k<<<11 * 25 * 4, 256, 0, stream>>>(x, w1b, shift, y1);

    sample_k<<<(4 * 2048) / 8, 224, 0, stream>>>(y1, ga, w2, out);
}

// Round 9
// 83.456 us; speedup vs baseline: 1.9195x; 1.0088x over previous
//
#include <hip/hip_runtime.h>
#include <hip/hip_bf16.h>

#define HH 200
#define WW 176
#define CIN 256
#define CO 28
#define BN_EPS 1e-3f

typedef __attribute__((ext_vector_type(8))) short short8;
typedef __attribute__((ext_vector_type(4))) float f32x4;

static __device__ __forceinline__ ushort f2bf(float f) {
    __hip_bfloat16 h = __float2bfloat16(f);
    return __builtin_bit_cast(ushort, h);
}

// ---------------------------------------------------------------------------
// prep: w1b chunk-major [h][t][n][lane][j] (bf16, BN-folded), plus shift[28].
//   co = n*16 + (lane&15), ci = h*32 + (lane>>4)*8 + j
// ---------------------------------------------------------------------------
__global__ void prep_k(const float* __restrict__ w1, const float* __restrict__ gamma,
                       const float* __restrict__ beta, const float* __restrict__ mean,
                       const float* __restrict__ var, ushort* __restrict__ w1b,
                       float* __restrict__ shift)
{
    int idx = blockIdx.x * 256 + threadIdx.x;
    if (idx < CO) {
        float sc = gamma[idx] * rsqrtf(var[idx] + BN_EPS);
        shift[idx] = beta[idx] - mean[idx] * sc;
    }
    if (idx < 8 * 9 * 2 * 64 * 8) {
        int j   = idx & 7;
        int l   = (idx >> 3) & 63;
        int n   = (idx >> 9) & 1;
        int rem = idx >> 10;          // h*9 + t
        int t   = rem % 9;
        int h   = rem / 9;
        int co = n * 16 + (l & 15);
        int ci = h * 32 + (l >> 4) * 8 + j;
        float v = 0.f;
        if (co < CO) {
            float sc = gamma[co] * rsqrtf(var[co] + BN_EPS);
            v = w1[(co * CIN + ci) * 9 + t] * sc;
        }
        w1b[idx] = f2bf(v);
    }
}

// ---------------------------------------------------------------------------
// Implicit-GEMM conv3x3 + BN + ReLU via bf16 MFMA.
// ALL hot-loop VMEM is volatile inline asm (cannot be sunk): weights ->
// VGPR b128, x -> VGPR dword. Hand-counted s_waitcnt vmcnt(N) carrying dest
// regs as "+v" operands; raw s_barrier (no auto vmcnt drain) -> loads stay in
// flight across barriers. One barrier per chunk.
// Tile 16x8 px, 4 waves; wave w owns rows {2w,2w+1}, stages ci-octet w.
// x halo 10x18 px (192-slot pad) x 32ci bf16, dbuf LDS, unit=(oct+(p>>1))&3
// swizzle (A-reads conflict-free).
// ---------------------------------------------------------------------------
__global__ __launch_bounds__(256, 3) void conv_mfma_k(
    const float* __restrict__ x, const ushort* __restrict__ w1b,
    const float* __restrict__ shift, float* __restrict__ y1)
{
    __shared__ uint4 sbuf[2][192 * 4];    // 2 x 12288 B

    const int tid  = threadIdx.x;
    const int lane = tid & 63;
    const int w    = tid >> 6;            // wave id == ci octet for staging
    const int wu   = __builtin_amdgcn_readfirstlane(w);
    const int c_   = lane & 15;
    const int oct  = lane >> 4;

    // XCD-aware bijective block swizzle (1100 blocks, 8 XCDs)
    const int NB = 11 * 25 * 4;
    const int q = NB / 8, r = NB % 8;     // 137, 4
    const int bid  = blockIdx.x;
    const int xcd  = bid & 7;
    const int rank = bid >> 3;
    const int tile = (xcd < r ? xcd * (q + 1) : r * (q + 1) + (xcd - r) * q) + rank;

    const int tx  = tile % 11;
    const int rem = tile / 11;
    const int ty  = rem % 25;
    const int b   = rem / 25;
    const int x0  = tx * 16, y0 = ty * 8;

    const float* xb = x + (size_t)b * CIN * HH * WW;

    // chunk-invariant per-lane staging geometry (halo 18 wide x 10 tall)
    int  soff[3]; bool sval[3];
#pragma unroll
    for (int it = 0; it < 3; ++it) {
        int p = it * 64 + lane;
        int rr = p / 18, cc = p - rr * 18;
        int gy = y0 + rr - 1, gx = x0 + cc - 1;
        bool v = (gy >= 0) & (gy < HH) & (gx >= 0) & (gx < WW);
        sval[it] = v;
        soff[it] = v ? gy * WW + gx : 0;
    }
    const uint voff0 = (uint)(soff[0] * 4);
    const uint voff1 = (uint)(soff[1] * 4);
    const uint voff2 = (uint)(soff[2] * 4);
    const uint wvoff = (uint)(lane * 16);

    float  xr[24];
    short8 wr[18];

    f32x4 acc[2][2];
#pragma unroll
    for (int m = 0; m < 2; ++m)
#pragma unroll
        for (int n = 0; n < 2; ++n)
            acc[m][n] = (f32x4){0.f, 0.f, 0.f, 0.f};

#define XLOAD(h)                                                              \
    {                                                                         \
        _Pragma("unroll")                                                     \
        for (int j = 0; j < 8; ++j) {                                         \
            const float* bj = xb + (size_t)((h) * 32 + wu * 8 + j) * 35200;   \
            asm volatile("global_load_dword %0, %1, %2"                       \
                         : "=v"(xr[0 + j]) : "v"(voff0), "s"(bj));            \
            asm volatile("global_load_dword %0, %1, %2"                       \
                         : "=v"(xr[8 + j]) : "v"(voff1), "s"(bj));            \
            asm volatile("global_load_dword %0, %1, %2"                       \
                         : "=v"(xr[16 + j]) : "v"(voff2), "s"(bj));           \
        }                                                                     \
    }

#define WLOAD(h)                                                              \
    {                                                                         \
        _Pragma("unroll")                                                     \
        for (int k = 0; k < 18; ++k) {                                        \
            const ushort* bk = w1b + (size_t)(h) * 9216 + k * 512;            \
            asm volatile("global_load_dwordx4 %0, %1, %2"                     \
                         : "=v"(wr[k]) : "v"(wvoff), "s"(bk));                \
        }                                                                     \
    }

// wait until W regs valid (24 x-loads may stay in flight); dest regs carried
#define WAITW(N)                                                              \
    asm volatile("s_waitcnt vmcnt(" #N ")"                                    \
        : "+v"(wr[0]), "+v"(wr[1]), "+v"(wr[2]), "+v"(wr[3]), "+v"(wr[4]),    \
          "+v"(wr[5]), "+v"(wr[6]), "+v"(wr[7]), "+v"(wr[8]));                \
    asm volatile("s_waitcnt vmcnt(" #N ")"                                    \
        : "+v"(wr[9]), "+v"(wr[10]), "+v"(wr[11]), "+v"(wr[12]),              \
          "+v"(wr[13]), "+v"(wr[14]), "+v"(wr[15]), "+v"(wr[16]),             \
          "+v"(wr[17]));                                                      \
    __builtin_amdgcn_sched_barrier(0);

#define WAITX()                                                               \
    asm volatile("s_waitcnt vmcnt(0)"                                         \
        : "+v"(xr[0]), "+v"(xr[1]), "+v"(xr[2]), "+v"(xr[3]), "+v"(xr[4]),    \
          "+v"(xr[5]), "+v"(xr[6]), "+v"(xr[7]), "+v"(xr[8]), "+v"(xr[9]),    \
          "+v"(xr[10]), "+v"(xr[11]));                                        \
    asm volatile("s_waitcnt vmcnt(0)"                                         \
        : "+v"(xr[12]), "+v"(xr[13]), "+v"(xr[14]), "+v"(xr[15]),             \
          "+v"(xr[16]), "+v"(xr[17]), "+v"(xr[18]), "+v"(xr[19]),             \
          "+v"(xr[20]), "+v"(xr[21]), "+v"(xr[22]), "+v"(xr[23]));            \
    __builtin_amdgcn_sched_barrier(0);

#define PACK_WR(BI)                                                           \
    {                                                                         \
        _Pragma("unroll")                                                     \
        for (int it = 0; it < 3; ++it) {                                      \
            int p = it * 64 + lane;                                           \
            ushort u[8];                                                      \
            _Pragma("unroll")                                                 \
            for (int j = 0; j < 8; ++j)                                       \
                u[j] = sval[it] ? f2bf(xr[it * 8 + j]) : (ushort)0;           \
            uint4 val;                                                        \
            val.x = (uint)u[0] | ((uint)u[1] << 16);                          \
            val.y = (uint)u[2] | ((uint)u[3] << 16);                          \
            val.z = (uint)u[4] | ((uint)u[5] << 16);                          \
            val.w = (uint)u[6] | ((uint)u[7] << 16);                          \
            sbuf[BI][p * 4 + ((w + (p >> 1)) & 3)] = val;                     \
        }                                                                     \
    }

#define COMPUTE(h)                                                            \
    {                                                                         \
        const uint4* sb = sbuf[(h) & 1];                                      \
        _Pragma("unroll")                                                     \
        for (int dx = 0; dx < 3; ++dx) {                                      \
            short8 av[4];                                                     \
            _Pragma("unroll")                                                 \
            for (int rl = 0; rl < 4; ++rl) {                                  \
                int p = (2 * w + rl) * 18 + c_ + dx;                          \
                av[rl] = __builtin_bit_cast(short8,                           \
                    sb[p * 4 + ((oct + (p >> 1)) & 3)]);                      \
            }                                                                 \
            _Pragma("unroll")                                                 \
            for (int dy = 0; dy < 3; ++dy) {                                  \
                const int t = dy * 3 + dx;                                    \
                _Pragma("unroll")                                             \
                for (int m = 0; m < 2; ++m) {                                 \
                    acc[m][0] = __builtin_amdgcn_mfma_f32_16x16x32_bf16(      \
                        av[m + dy], wr[t * 2 + 0], acc[m][0], 0, 0, 0);       \
                    acc[m][1] = __builtin_amdgcn_mfma_f32_16x16x32_bf16(      \
                        av[m + dy], wr[t * 2 + 1], acc[m][1], 0, 0, 0);       \
                }                                                             \
            }                                                                 \
        }                                                                     \
    }

#define BODY(h)                                                               \
    {                                                                         \
        XLOAD((h) + 1);                                                       \
        WAITW(24)                                                             \
        COMPUTE(h);                                                           \
        WAITX()                                                               \
        PACK_WR(((h) + 1) & 1);                                               \
        WLOAD((h) + 1);                                                       \
        asm volatile("s_waitcnt lgkmcnt(0)");                                 \
        __builtin_amdgcn_sched_barrier(0);                                    \
        __builtin_amdgcn_s_barrier();                                         \
    }

    // prologue: W(0)+x(0) in flight, drain all, stage x(0), barrier
    WLOAD(0);
    XLOAD(0);
    WAITW(0)
    WAITX()
    PACK_WR(0);
    asm volatile("s_waitcnt lgkmcnt(0)");
    __builtin_amdgcn_sched_barrier(0);
    __builtin_amdgcn_s_barrier();

    BODY(0) BODY(1) BODY(2) BODY(3) BODY(4) BODY(5) BODY(6)
    // last chunk: nothing to prefetch
    WAITW(0)
    COMPUTE(7);

    // epilogue: + shift, ReLU, store channel-last y1
    const int co0 = c_;
    const int co1 = 16 + c_;
    const float s0 = shift[co0];
    const float s1 = (co1 < CO) ? shift[co1] : 0.f;
#pragma unroll
    for (int m = 0; m < 2; ++m) {
        int gy = y0 + 2 * w + m;
#pragma unroll
        for (int reg = 0; reg < 4; ++reg) {
            int gx = x0 + oct * 4 + reg;
            float* yp = y1 + ((size_t)(b * HH + gy) * WW + gx) * CO;
            float v0 = acc[m][0][reg] + s0;
            yp[co0] = v0 > 0.f ? v0 : 0.f;
            if (co1 < CO) {
                float v1 = acc[m][1][reg] + s1;
                yp[co1] = v1 > 0.f ? v1 : 0.f;
            }
        }
    }
}

// ---------------------------------------------------------------------------
// Sampler: thread = (box, k).  Bilinear sample of conv1x1 output = conv1x1 of
// bilinear samples (linear, bias-free).  Mean over k via LDS reduce.
// ---------------------------------------------------------------------------
__global__ __launch_bounds__(224) void sample_k(
    const float* __restrict__ y1, const float* __restrict__ ga,
    const float* __restrict__ w2, float* __restrict__ out)
{
    __shared__ float red[224];
    const int lb  = threadIdx.x / CO;   // local box 0..7
    const int k   = threadIdx.x % CO;   // window index / channel
    const int box = blockIdx.x * 8 + lb;
    const int b   = box >> 11;          // / 2048

    const float* ap = ga + (size_t)box * 7;
    float xg = ap[0], yg = ap[1], wg = ap[3], lg = ap[4], rg = ap[6];
    float c = cosf(rg), s = sinf(rg);

    const int i = k / 7, j = k % 7;
    float xx = ((float)i * (1.f / 3.f) - 0.5f) * wg;
    float yy = ((float)j * (1.f / 6.f) - 0.5f) * lg;
    float xs = (xx * c + yy * s + xg) * 2.5f;
    float ys = (yy * c - xx * s + yg + 40.f) * 2.5f;

    float x0 = floorf(xs), y0 = floorf(ys);
    float wx = xs - x0,    wy = ys - y0;

    float w2r[CO];
    const float* w2p = w2 + k * CO;
#pragma unroll
    for (int q = 0; q < 7; ++q) {
        float4 t = ((const float4*)w2p)[q];
        w2r[4*q] = t.x; w2r[4*q+1] = t.y; w2r[4*q+2] = t.z; w2r[4*q+3] = t.w;
    }

    float val = 0.f;
    const float* yb = y1 + (size_t)b * HH * WW * CO;
#pragma unroll
    for (int cor = 0; cor < 4; ++cor) {
        float yf = y0 + (float)(cor >> 1);
        float xf = x0 + (float)(cor & 1);
        float cw = ((cor & 1) ? wx : 1.f - wx) * ((cor >> 1) ? wy : 1.f - wy);
        if (yf >= 0.f && yf <= (float)(HH - 1) && xf >= 0.f && xf <= (float)(WW - 1)) {
            int yi = (int)yf, xi = (int)xf;
            const float* p = yb + ((size_t)yi * WW + xi) * CO;
            float d = 0.f;
#pragma unroll
            for (int q = 0; q < 7; ++q) {
                float4 t = ((const float4*)p)[q];
                d = fmaf(w2r[4*q],   t.x, d);
                d = fmaf(w2r[4*q+1], t.y, d);
                d = fmaf(w2r[4*q+2], t.z, d);
                d = fmaf(w2r[4*q+3], t.w, d);
            }
            val = fmaf(cw, d, val);
        }
    }

    red[threadIdx.x] = val;
    __syncthreads();
    if (k == 0) {
        float sum = 0.f;
#pragma unroll
        for (int q = 0; q < CO; ++q) sum += red[lb * CO + q];
        out[box] = sum * (1.f / 28.f);
    }
}

// ---------------------------------------------------------------------------
extern "C" void kernel_launch(void* const* d_in, const int* in_sizes, int n_in,
                              void* d_out, int out_size, void* d_ws, size_t ws_size,
                              hipStream_t stream) {
    const float* x     = (const float*)d_in[0];
    const float* ga    = (const float*)d_in[1];
    const float* w1    = (const float*)d_in[2];
    const float* gamma = (const float*)d_in[3];
    const float* beta  = (const float*)d_in[4];
    const float* mean  = (const float*)d_in[5];
    const float* var   = (const float*)d_in[6];
    const float* w2    = (const float*)d_in[7];
    float* out = (float*)d_out;

    ushort* w1b   = (ushort*)d_ws;                         // 147456 B
    float*  shift = (float*)((char*)d_ws + 147456);        // 112 B
    float*  y1    = (float*)((char*)d_ws + 147968);        // 4*200*176*28 f32

    prep_k<<<(8 * 9 * 2 * 64 * 8 + 255) / 256, 256, 0, stream>>>(
        w1, gamma, beta, mean, var, w1b, shift);

    conv_mfma_k<<<11 * 25 * 4, 256, 0, stream>>>(x, w1b, shift, y1);

    sample_k<<<(4 * 2048) / 8, 224, 0, stream>>>(y1, ga, w2, out);
}

// Round 11
// 75.508 us; speedup vs baseline: 2.1215x; 1.1053x over previous
//
#include <hip/hip_runtime.h>
#include <hip/hip_bf16.h>

#define HH 200
#define WW 176
#define CIN 256
#define CO 28
#define BN_EPS 1e-3f

typedef __attribute__((ext_vector_type(8))) short short8;
typedef __attribute__((ext_vector_type(4))) float f32x4;

static __device__ __forceinline__ ushort f2bf(float f) {
    __hip_bfloat16 h = __float2bfloat16(f);
    return __builtin_bit_cast(ushort, h);
}

// ---------------------------------------------------------------------------
// prep: w1b chunk-major [h][t][n][lane][j] (bf16, BN-folded), plus shift[28].
//   co = n*16 + (lane&15), ci = h*32 + (lane>>4)*8 + j
// ---------------------------------------------------------------------------
__global__ void prep_k(const float* __restrict__ w1, const float* __restrict__ gamma,
                       const float* __restrict__ beta, const float* __restrict__ mean,
                       const float* __restrict__ var, ushort* __restrict__ w1b,
                       float* __restrict__ shift)
{
    int idx = blockIdx.x * 256 + threadIdx.x;
    if (idx < CO) {
        float sc = gamma[idx] * rsqrtf(var[idx] + BN_EPS);
        shift[idx] = beta[idx] - mean[idx] * sc;
    }
    if (idx < 8 * 9 * 2 * 64 * 8) {
        int j   = idx & 7;
        int l   = (idx >> 3) & 63;
        int n   = (idx >> 9) & 1;
        int rem = idx >> 10;          // h*9 + t
        int t   = rem % 9;
        int h   = rem / 9;
        int co = n * 16 + (l & 15);
        int ci = h * 32 + (l >> 4) * 8 + j;
        float v = 0.f;
        if (co < CO) {
            float sc = gamma[co] * rsqrtf(var[co] + BN_EPS);
            v = w1[(co * CIN + ci) * 9 + t] * sc;
        }
        w1b[idx] = f2bf(v);
    }
}

// ---------------------------------------------------------------------------
// Implicit-GEMM conv3x3 + BN + ReLU, ci-SPLIT across waves.
// Tile 16x8 px. Wave w owns LDS buffer w exclusively and processes ci-chunks
// {w, 4+w} END-TO-END (stage + compute) -> ZERO barriers in the hot path;
// waves drift freely so TLP hides memory latency. Each wave computes the FULL
// 8 M-frags x 2 N-frags (partial over its 64 ci); partials combined at the
// end via a 2-barrier LDS reduction.
// All chunk indices passed to asm address math use wave-uniform wu
// (readfirstlane) so "s" constraints resolve to SGPR pairs.
// ---------------------------------------------------------------------------
__global__ __launch_bounds__(256, 2) void conv_mfma_k(
    const float* __restrict__ x, const ushort* __restrict__ w1b,
    const float* __restrict__ shift, float* __restrict__ y1)
{
    __shared__ uint4 sbuf[4][768];        // 4 x 12288 B, wave-private

    const int tid  = threadIdx.x;
    const int lane = tid & 63;
    const int w    = tid >> 6;            // wave id
    const int wu   = __builtin_amdgcn_readfirstlane(w);
    const int c_   = lane & 15;
    const int oct  = lane >> 4;

    // XCD-aware bijective block swizzle (1100 blocks, 8 XCDs)
    const int NB = 11 * 25 * 4;
    const int q = NB / 8, r = NB % 8;     // 137, 4
    const int bid  = blockIdx.x;
    const int xcd  = bid & 7;
    const int rank = bid >> 3;
    const int tile = (xcd < r ? xcd * (q + 1) : r * (q + 1) + (xcd - r) * q) + rank;

    const int tx  = tile % 11;
    const int rem = tile / 11;
    const int ty  = rem % 25;
    const int b   = rem / 25;
    const int x0  = tx * 16, y0 = ty * 8;

    const float* xb = x + (size_t)b * CIN * HH * WW;

    // chunk-invariant per-lane staging geometry (halo 18 wide x 10 tall)
    int  soff[3]; bool sval[3];
#pragma unroll
    for (int it = 0; it < 3; ++it) {
        int p = it * 64 + lane;
        int rr = p / 18, cc = p - rr * 18;
        int gy = y0 + rr - 1, gx = x0 + cc - 1;
        bool v = (gy >= 0) & (gy < HH) & (gx >= 0) & (gx < WW);
        sval[it] = v;
        soff[it] = v ? gy * WW + gx : 0;
    }
    const uint voff0 = (uint)(soff[0] * 4);
    const uint voff1 = (uint)(soff[1] * 4);
    const uint voff2 = (uint)(soff[2] * 4);
    const uint wvoff = (uint)(lane * 16);

    float  xA[24], xB[24];
    short8 wqA[6], wqB[6];

    f32x4 acc[8][2];
#pragma unroll
    for (int m = 0; m < 8; ++m)
#pragma unroll
        for (int n = 0; n < 2; ++n)
            acc[m][n] = (f32x4){0.f, 0.f, 0.f, 0.f};

// 24 x-loads for ci-octet o of chunk ch (ch MUST be wave-uniform)
#define ISSUE24(ch, o, XR)                                                    \
    {                                                                         \
        _Pragma("unroll")                                                     \
        for (int j = 0; j < 8; ++j) {                                         \
            const float* bj = xb + (size_t)((ch) * 32 + (o) * 8 + j) * 35200; \
            asm volatile("global_load_dword %0, %1, %2"                       \
                         : "=v"(XR[0 + j]) : "v"(voff0), "s"(bj));            \
            asm volatile("global_load_dword %0, %1, %2"                       \
                         : "=v"(XR[8 + j]) : "v"(voff1), "s"(bj));            \
            asm volatile("global_load_dword %0, %1, %2"                       \
                         : "=v"(XR[16 + j]) : "v"(voff2), "s"(bj));           \
        }                                                                     \
    }

// wait until at most N VMEM outstanding; carry XR[24] as operands
#define WAITX(N, XR)                                                          \
    asm volatile("s_waitcnt vmcnt(" #N ")"                                    \
        : "+v"(XR[0]), "+v"(XR[1]), "+v"(XR[2]), "+v"(XR[3]), "+v"(XR[4]),    \
          "+v"(XR[5]), "+v"(XR[6]), "+v"(XR[7]), "+v"(XR[8]), "+v"(XR[9]),    \
          "+v"(XR[10]), "+v"(XR[11]));                                        \
    asm volatile("s_waitcnt vmcnt(" #N ")"                                    \
        : "+v"(XR[12]), "+v"(XR[13]), "+v"(XR[14]), "+v"(XR[15]),             \
          "+v"(XR[16]), "+v"(XR[17]), "+v"(XR[18]), "+v"(XR[19]),             \
          "+v"(XR[20]), "+v"(XR[21]), "+v"(XR[22]), "+v"(XR[23]));            \
    __builtin_amdgcn_sched_barrier(0);

// convert + pack + ds_write octet o into wave-private buffer
#define PACK(XR, o)                                                           \
    {                                                                         \
        _Pragma("unroll")                                                     \
        for (int it = 0; it < 3; ++it) {                                      \
            int p = it * 64 + lane;                                           \
            ushort u[8];                                                      \
            _Pragma("unroll")                                                 \
            for (int j = 0; j < 8; ++j)                                       \
                u[j] = sval[it] ? f2bf(XR[it * 8 + j]) : (ushort)0;           \
            uint4 val;                                                        \
            val.x = (uint)u[0] | ((uint)u[1] << 16);                          \
            val.y = (uint)u[2] | ((uint)u[3] << 16);                          \
            val.z = (uint)u[4] | ((uint)u[5] << 16);                          \
            val.w = (uint)u[6] | ((uint)u[7] << 16);                          \
            sbuf[w][p * 4 + (((o) + (p >> 1)) & 3)] = val;                    \
        }                                                                     \
    }

// 6 weight-frag loads for column dx of chunk ch (ch wave-uniform)
#define WLOAD6(ch, dx, WQ)                                                    \
    {                                                                         \
        const ushort* wbase = w1b + (size_t)(ch) * 9216;                      \
        _Pragma("unroll")                                                     \
        for (int dy = 0; dy < 3; ++dy) {                                      \
            _Pragma("unroll")                                                 \
            for (int n = 0; n < 2; ++n) {                                     \
                const ushort* bk = wbase + (size_t)((dy * 3 + (dx)) * 2 + n) * 512; \
                asm volatile("global_load_dwordx4 %0, %1, %2"                 \
                             : "=v"(WQ[dy * 2 + n]) : "v"(wvoff), "s"(bk));   \
            }                                                                 \
        }                                                                     \
    }

#define WAITW(N, WQ)                                                          \
    asm volatile("s_waitcnt vmcnt(" #N ")"                                    \
        : "+v"(WQ[0]), "+v"(WQ[1]), "+v"(WQ[2]), "+v"(WQ[3]), "+v"(WQ[4]),    \
          "+v"(WQ[5]));                                                       \
    __builtin_amdgcn_sched_barrier(0);

// 10 A-frag ds_reads + 48 MFMA for column dx
#define COMP_DX(dx, WQ)                                                       \
    {                                                                         \
        short8 av[10];                                                        \
        _Pragma("unroll")                                                     \
        for (int rr = 0; rr < 10; ++rr) {                                     \
            int p = rr * 18 + c_ + (dx);                                      \
            av[rr] = __builtin_bit_cast(short8,                               \
                sbuf[w][p * 4 + ((oct + (p >> 1)) & 3)]);                     \
        }                                                                     \
        _Pragma("unroll")                                                     \
        for (int dy = 0; dy < 3; ++dy) {                                      \
            _Pragma("unroll")                                                 \
            for (int m = 0; m < 8; ++m) {                                     \
                acc[m][0] = __builtin_amdgcn_mfma_f32_16x16x32_bf16(          \
                    av[m + dy], WQ[dy * 2 + 0], acc[m][0], 0, 0, 0);          \
                acc[m][1] = __builtin_amdgcn_mfma_f32_16x16x32_bf16(          \
                    av[m + dy], WQ[dy * 2 + 1], acc[m][1], 0, 0, 0);          \
            }                                                                 \
        }                                                                     \
    }

// stage chunk ch into wave-private buffer (ping-pong octet batches),
// tail pre-issues W(dx=0) into wqA
#define STAGE(ch)                                                             \
    {                                                                         \
        ISSUE24(ch, 0, xA); ISSUE24(ch, 1, xB);                               \
        WAITX(24, xA) PACK(xA, 0);                                            \
        ISSUE24(ch, 2, xA);                                                   \
        WAITX(24, xB) PACK(xB, 1);                                            \
        ISSUE24(ch, 3, xB);                                                   \
        WAITX(24, xA) PACK(xA, 2);                                            \
        WLOAD6(ch, 0, wqA);                                                   \
        WAITX(6, xB) PACK(xB, 3);                                             \
    }

// compute chunk ch (expects W(dx0) in flight in wqA)
#define COMPCH(ch)                                                            \
    {                                                                         \
        WLOAD6(ch, 1, wqB);                                                   \
        WAITW(6, wqA) COMP_DX(0, wqA);                                        \
        WLOAD6(ch, 2, wqA);                                                   \
        WAITW(6, wqB) COMP_DX(1, wqB);                                        \
        WAITW(0, wqA) COMP_DX(2, wqA);                                        \
    }

    STAGE(wu)
    COMPCH(wu)
    STAGE(wu + 4)
    COMPCH(wu + 4)

    // -------- cross-wave ci-reduction (the only barriers in the kernel)
    __syncthreads();                      // all waves done with their sbuf
    f32x4* rb = (f32x4*)&sbuf[0][0];      // 3072 f32x4 slots = 48 KB
    if (w > 0) {
        int base = (w - 1) * 1024 + lane;
#pragma unroll
        for (int m = 0; m < 8; ++m)
#pragma unroll
            for (int n = 0; n < 2; ++n)
                rb[base + (m * 2 + n) * 64] = acc[m][n];
    }
    __syncthreads();
    if (w == 0) {
        const float s0 = shift[c_];
        const float s1 = (16 + c_ < CO) ? shift[16 + c_] : 0.f;
#pragma unroll
        for (int m = 0; m < 8; ++m) {
            int gy = y0 + m;
#pragma unroll
            for (int n = 0; n < 2; ++n) {
                f32x4 s = acc[m][n];
#pragma unroll
                for (int v = 1; v < 4; ++v)
                    s += rb[(v - 1) * 1024 + (m * 2 + n) * 64 + lane];
                const float sh = n ? s1 : s0;
                const int co = n * 16 + c_;
                if (co < CO) {
#pragma unroll
                    for (int reg = 0; reg < 4; ++reg) {
                        int gx = x0 + oct * 4 + reg;
                        float* yp = y1 + ((size_t)(b * HH + gy) * WW + gx) * CO;
                        float vv = s[reg] + sh;
                        yp[co] = vv > 0.f ? vv : 0.f;
                    }
                }
            }
        }
    }
}

// ---------------------------------------------------------------------------
// Sampler: thread = (box, k).  Bilinear sample of conv1x1 output = conv1x1 of
// bilinear samples (linear, bias-free).  Mean over k via LDS reduce.
// ---------------------------------------------------------------------------
__global__ __launch_bounds__(224) void sample_k(
    const float* __restrict__ y1, const float* __restrict__ ga,
    const float* __restrict__ w2, float* __restrict__ out)
{
    __shared__ float red[224];
    const int lb  = threadIdx.x / CO;   // local box 0..7
    const int k   = threadIdx.x % CO;   // window index / channel
    const int box = blockIdx.x * 8 + lb;
    const int b   = box >> 11;          // / 2048

    const float* ap = ga + (size_t)box * 7;
    float xg = ap[0], yg = ap[1], wg = ap[3], lg = ap[4], rg = ap[6];
    float c = cosf(rg), s = sinf(rg);

    const int i = k / 7, j = k % 7;
    float xx = ((float)i * (1.f / 3.f) - 0.5f) * wg;
    float yy = ((float)j * (1.f / 6.f) - 0.5f) * lg;
    float xs = (xx * c + yy * s + xg) * 2.5f;
    float ys = (yy * c - xx * s + yg + 40.f) * 2.5f;

    float x0 = floorf(xs), y0 = floorf(ys);
    float wx = xs - x0,    wy = ys - y0;

    float w2r[CO];
    const float* w2p = w2 + k * CO;
#pragma unroll
    for (int q = 0; q < 7; ++q) {
        float4 t = ((const float4*)w2p)[q];
        w2r[4*q] = t.x; w2r[4*q+1] = t.y; w2r[4*q+2] = t.z; w2r[4*q+3] = t.w;
    }

    float val = 0.f;
    const float* yb = y1 + (size_t)b * HH * WW * CO;
#pragma unroll
    for (int cor = 0; cor < 4; ++cor) {
        float yf = y0 + (float)(cor >> 1);
        float xf = x0 + (float)(cor & 1);
        float cw = ((cor & 1) ? wx : 1.f - wx) * ((cor >> 1) ? wy : 1.f - wy);
        if (yf >= 0.f && yf <= (float)(HH - 1) && xf >= 0.f && xf <= (float)(WW - 1)) {
            int yi = (int)yf, xi = (int)xf;
            const float* p = yb + ((size_t)yi * WW + xi) * CO;
            float d = 0.f;
#pragma unroll
            for (int q = 0; q < 7; ++q) {
                float4 t = ((const float4*)p)[q];
                d = fmaf(w2r[4*q],   t.x, d);
                d = fmaf(w2r[4*q+1], t.y, d);
                d = fmaf(w2r[4*q+2], t.z, d);
                d = fmaf(w2r[4*q+3], t.w, d);
            }
            val = fmaf(cw, d, val);
        }
    }

    red[threadIdx.x] = val;
    __syncthreads();
    if (k == 0) {
        float sum = 0.f;
#pragma unroll
        for (int q = 0; q < CO; ++q) sum += red[lb * CO + q];
        out[box] = sum * (1.f / 28.f);
    }
}

// ---------------------------------------------------------------------------
extern "C" void kernel_launch(void* const* d_in, const int* in_sizes, int n_in,
                              void* d_out, int out_size, void* d_ws, size_t ws_size,
                              hipStream_t stream) {
    const float* x     = (const float*)d_in[0];
    const float* ga    = (const float*)d_in[1];
    const float* w1    = (const float*)d_in[2];
    const float* gamma = (const float*)d_in[3];
    const float* beta  = (const float*)d_in[4];
    const float* mean  = (const float*)d_in[5];
    const float* var   = (const float*)d_in[6];
    const float* w2    = (const float*)d_in[7];
    float* out = (float*)d_out;

    ushort* w1b   = (ushort*)d_ws;                         // 147456 B
    float*  shift = (float*)((char*)d_ws + 147456);        // 112 B
    float*  y1    = (float*)((char*)d_ws + 147968);        // 4*200*176*28 f32

    prep_k<<<(8 * 9 * 2 * 64 * 8 + 255) / 256, 256, 0, stream>>>(
        w1, gamma, beta, mean, var, w1b, shift);

    conv_mfma_k<<<11 * 25 * 4, 256, 0, stream>>>(x, w1b, shift, y1);

    sample_k<<<(4 * 2048) / 8, 224, 0, stream>>>(y1, ga, w2, out);
}